// Round 7
// baseline (219.029 us; speedup 1.0000x reference)
//
#include <hip/hip_runtime.h>
#include <cstdint>
#include <cstddef>

#define BT_TOTAL 76800   // 128*600 cells
#define NCLS 13
#define IGN  (-100)

// ---- kernel A: targets ----
#define CPA   32                 // cells per block
#define NBLKA (BT_TOTAL / CPA)   // 2400
#define NF4A  (CPA * 195 / 4)    // 1560 float4
#define KA    7                  // ceil(1560/256)
// ---- kernel B: loss ----
#define CPB   32                 // cells per block
#define NBLKB (BT_TOTAL / CPB)   // 2400
#define ITEMS (CPB * 6)          // 192
#define NF4B  (CPB * 234 / 4)    // 1872 float4
#define KB    8                  // ceil(1872/256)

// d_ws layout:
//   [0 .. TGT_BYTES)                 uint2 packed targets {ta bytes, tb bytes}
//   [TGT_BYTES .. +NBLKB*16)         Partial per block
//   [TGT_BYTES+NBLKB*16 .. +4)       int ticket counter (zeroed by kernel A)
#define TGT_BYTES ((size_t)BT_TOTAL * 6 * sizeof(uint2))   // 3,686,400

struct Partial { float ls; int lc; int cor; int val; };

// async global->LDS DMA, 16B per lane; dest = wave-uniform base + lane*16
__device__ __forceinline__ void stage16(const float4* __restrict__ g, float4* l) {
    __builtin_amdgcn_global_load_lds((const __attribute__((address_space(1))) void*)g,
                                     (__attribute__((address_space(3))) void*)l,
                                     16, 0, 0);
}

// ================= Kernel A: TDOA targets =================
extern "C" __global__ __launch_bounds__(256)
void tdoa_targets(const float* __restrict__ target, uint2* __restrict__ wsT,
                  int* __restrict__ counter) {
    const int tid = threadIdx.x;
    const int cb  = blockIdx.x * CPA;

    if (blockIdx.x == 0 && tid == 0) *counter = 0;   // ticket for kernel B's last-block reduce

    __shared__ float4 sA4[NF4A];   // 24,960 B -> 6 blocks/CU
    const float* sA = (const float*)sA4;

    {
        const float4* g = (const float4*)(target + (size_t)cb * 195);
#pragma unroll
        for (int k = 0; k < KA; k++) {
            const int i = k * 256 + tid;
            if (i < NF4A) stage16(g + i, &sA4[i]);
        }
    }
    __syncthreads();   // drains the global_load_lds queue

    if (tid < CPA) {
        const float* tg = sA + tid * 195;   // [e][f][c] : e*65 + f*13 + c

        const float MX[4] = { 0.02432757455f,  0.02432757455f, -0.02432757455f, -0.02432757455f };
        const float MY[4] = { 0.02432757455f, -0.02432757455f,  0.02432757455f, -0.02432757455f };
        const float MZ[4] = { 0.02409021033f, -0.02409021033f, -0.02409021033f,  0.02409021033f };
        const int PI_[6] = {0,0,0,1,1,2};
        const int PJ_[6] = {1,2,3,2,3,3};

        int  td[3][6];
        bool ab[3];
        int  nact = 0;
#pragma unroll
        for (int e = 0; e < 3; e++) {
            float a[NCLS];
#pragma unroll
            for (int c = 0; c < NCLS; c++) a[c] = tg[e * 65 + c];
            bool ia = false;
#pragma unroll
            for (int c = 0; c < NCLS; c++) ia = ia || (a[c] > 0.0f);
            float d0 = 0.f, d1 = 0.f, d2 = 0.f, ds = 0.f;
#pragma unroll
            for (int c = 0; c < NCLS; c++) {
                d0 += a[c] * tg[e * 65 + 13 + c];
                d1 += a[c] * tg[e * 65 + 26 + c];
                d2 += a[c] * tg[e * 65 + 39 + c];
                ds += a[c] * tg[e * 65 + 52 + c];
            }
            const float sx = d0 * ds, sy = d1 * ds, sz = d2 * ds;
            float dm[4];
#pragma unroll
            for (int m = 0; m < 4; m++) {
                const float ex = sx - MX[m], ey = sy - MY[m], ez = sz - MZ[m];
                dm[m] = sqrtf(ex * ex + ey * ey + ez * ez);
            }
#pragma unroll
            for (int p = 0; p < 6; p++) {
                const float diff = dm[PI_[p]] - dm[PJ_[p]];
                td[e][p] = (int)rintf((diff * 24000.0f) / 343.0f) + 6;  // MAX_TAU=6
            }
            ab[e] = ia;
            nact += ia ? 1 : 0;
        }

        // stable argsort(!is_active) for E=3: actives first, original order
        const int o0 = ab[0] ? 0 : (ab[1] ? 1 : 2);
        const int o1 = (ab[0] && ab[1]) ? 1 : 2;
        const bool empty = (nact == 0);

#pragma unroll
        for (int p = 0; p < 6; p++) {
            const int g0 = (o0 == 0) ? td[0][p] : ((o0 == 1) ? td[1][p] : td[2][p]);
            const int g1 = (o1 == 1) ? td[1][p] : td[2][p];
            const int g2 = td[2][p];
            // idx1 = clip(min(k, n-1), 0, 2); idx2 = (k < n) ? k : 0
            int ta0 = g0;
            int ta1 = (nact >= 2) ? g1 : g0;
            int ta2 = (nact == 3) ? g2 : ((nact == 2) ? g1 : g0);
            int tb0 = g0;
            int tb1 = (nact >= 2) ? g1 : g0;
            int tb2 = (nact == 3) ? g2 : g0;
            uint32_t w0 = (uint32_t)(ta0 & 0xff) | ((uint32_t)(ta1 & 0xff) << 8) | ((uint32_t)(ta2 & 0xff) << 16);
            uint32_t w1 = (uint32_t)(tb0 & 0xff) | ((uint32_t)(tb1 & 0xff) << 8) | ((uint32_t)(tb2 & 0xff) << 16);
            if (empty) { w0 = 0x009c9c9cu; w1 = 0x009c9c9cu; }   // 0x9c == (int8)-100
            wsT[(size_t)(cb + tid) * 6 + p] = make_uint2(w0, w1);
        }
    }
}

// ================= Kernel B: PIT loss (+ inline final reduce) =================
extern "C" __global__ __launch_bounds__(256)
void tdoa_loss(const float* __restrict__ pred, const uint2* __restrict__ wsT,
               Partial* __restrict__ part, int* __restrict__ counter,
               float* __restrict__ out) {
    const int tid = threadIdx.x;
    const int cb  = blockIdx.x * CPB;

    __shared__ float4 sP4[NF4B];   // 29,952 B -> 5 blocks/CU
    const float* sP = (const float*)sP4;

    {
        const float4* g = (const float4*)(pred + (size_t)cb * 234);
#pragma unroll
        for (int k = 0; k < KB; k++) {
            const int i = k * 256 + tid;
            if (i < NF4B) stage16(g + i, &sP4[i]);
        }
    }
    __syncthreads();   // drains the global_load_lds queue

    float lsum = 0.f;
    int   lcnt = 0, cor = 0, nval = 0;

    if (tid < ITEMS) {
        const int btl = tid / 6;
        const int p   = tid - btl * 6;
        const float* pp = sP + btl * 234 + p;   // [c][tr][p] strides 18,6,1

        float x[NCLS][3];
#pragma unroll
        for (int c = 0; c < NCLS; c++)
#pragma unroll
            for (int j = 0; j < 3; j++)
                x[c][j] = pp[c * 18 + j * 6];

        int   am[3];
        float lse[3];
#pragma unroll
        for (int j = 0; j < 3; j++) {
            float m = x[0][j]; int a = 0;
#pragma unroll
            for (int c = 1; c < NCLS; c++) { if (x[c][j] > m) { m = x[c][j]; a = c; } }
            float s = 0.f;
#pragma unroll
            for (int c = 0; c < NCLS; c++) s += expf(x[c][j] - m);
            am[j] = a; lse[j] = m + logf(s);
        }

        const uint2 tw = wsT[(size_t)(cb + btl) * 6 + p];   // coalesced dwordx2
        int ta[3], tb[3];
#pragma unroll
        for (int i = 0; i < 3; i++) {
            ta[i] = (int)(int8_t)(tw.x >> (8 * i));
            tb[i] = (int)(int8_t)(tw.y >> (8 * i));
        }

        // indexed LDS reads instead of 13-deep cndmask select chains
        float La[3][3], Lb[3][3];
#pragma unroll
        for (int i = 0; i < 3; i++) {
            const int  ca  = (ta[i] < 0) ? 0 : ta[i];
            const int  cb2 = (tb[i] < 0) ? 0 : tb[i];
            const bool ia  = (ta[i] == IGN);
            const bool ib  = (tb[i] == IGN);
#pragma unroll
            for (int j = 0; j < 3; j++) {
                La[i][j] = ia ? 0.f : (lse[j] - pp[ca  * 18 + j * 6]);
                Lb[i][j] = ib ? 0.f : (lse[j] - pp[cb2 * 18 + j * 6]);
            }
        }

        const int P0[6] = {0,0,1,1,2,2};
        const int P1[6] = {1,2,0,2,0,1};
        const int P2[6] = {2,1,2,0,1,0};
        float l1 = 0.f, l2 = 0.f; int i1 = 0, i2 = 0;
#pragma unroll
        for (int q = 0; q < 6; q++) {
            const float va = (La[0][P0[q]] + La[1][P1[q]] + La[2][P2[q]]) * (1.0f / 3.0f);
            const float vb = (Lb[0][P0[q]] + Lb[1][P1[q]] + Lb[2][P2[q]]) * (1.0f / 3.0f);
            if (q == 0) { l1 = va; l2 = vb; }
            else {
                if (va < l1) { l1 = va; i1 = q; }
                if (vb < l2) { l2 = vb; i2 = q; }
            }
        }

        const bool use2 = (l2 < l1);
        const float loss = use2 ? l2 : l1;
        const int  qsel = use2 ? i2 : i1;
        const int PK[6] = {36, 24, 33, 9, 18, 6};   // p0 | p1<<2 | p2<<4
        int pk = PK[0];
#pragma unroll
        for (int k = 1; k < 6; k++) pk = (qsel == k) ? PK[k] : pk;
        const int s0 = use2 ? tb[0] : ta[0];
        const int s1 = use2 ? tb[1] : ta[1];
        const int s2 = use2 ? tb[2] : ta[2];
#pragma unroll
        for (int i = 0; i < 3; i++) {
            const int pi = (pk >> (2 * i)) & 3;
            const int tp = (pi == 0) ? s0 : ((pi == 1) ? s1 : s2);
            const bool v = (tp != IGN);
            nval += v ? 1 : 0;
            cor  += (v && (am[i] == tp)) ? 1 : 0;
        }
        if (loss > 0.f) { lsum += loss; lcnt++; }
    }

    // block reduction (4 waves) -> per-block partial
#pragma unroll
    for (int off = 32; off > 0; off >>= 1) {
        lsum += __shfl_down(lsum, off, 64);
        lcnt += __shfl_down(lcnt, off, 64);
        cor  += __shfl_down(cor,  off, 64);
        nval += __shfl_down(nval, off, 64);
    }
    __shared__ float rf[4];
    __shared__ int   r1[4], r2[4], r3[4];
    __shared__ int   sLast;
    const int wid = tid >> 6;
    if ((tid & 63) == 0) { rf[wid] = lsum; r1[wid] = lcnt; r2[wid] = cor; r3[wid] = nval; }
    __syncthreads();
    if (tid == 0) {
        Partial pt;
        pt.ls  = rf[0] + rf[1] + rf[2] + rf[3];
        pt.lc  = r1[0] + r1[1] + r1[2] + r1[3];
        pt.cor = r2[0] + r2[1] + r2[2] + r2[3];
        pt.val = r3[0] + r3[1] + r3[2] + r3[3];
        part[blockIdx.x] = pt;
        __threadfence();   // release: make the partial visible device-wide
        const int ticket = atomicAdd(counter, 1);
        sLast = (ticket == NBLKB - 1) ? 1 : 0;
    }
    __syncthreads();

    // last finishing block performs the final reduce (saves a launch)
    if (sLast) {
        double ls = 0.0; int lc = 0, cr = 0, vl = 0;
        for (int i = tid; i < NBLKB; i += 256) {
            const uint32_t* q = (const uint32_t*)&part[i];
            const uint32_t a0 = __hip_atomic_load(q + 0, __ATOMIC_RELAXED, __HIP_MEMORY_SCOPE_AGENT);
            const uint32_t a1 = __hip_atomic_load(q + 1, __ATOMIC_RELAXED, __HIP_MEMORY_SCOPE_AGENT);
            const uint32_t a2 = __hip_atomic_load(q + 2, __ATOMIC_RELAXED, __HIP_MEMORY_SCOPE_AGENT);
            const uint32_t a3 = __hip_atomic_load(q + 3, __ATOMIC_RELAXED, __HIP_MEMORY_SCOPE_AGENT);
            ls += (double)__uint_as_float(a0);
            lc += (int)a1; cr += (int)a2; vl += (int)a3;
        }
#pragma unroll
        for (int off = 32; off > 0; off >>= 1) {
            ls += __shfl_down(ls, off, 64);
            lc += __shfl_down(lc, off, 64);
            cr += __shfl_down(cr, off, 64);
            vl += __shfl_down(vl, off, 64);
        }
        __shared__ double sd[4];
        __shared__ int    s1a[4], s2a[4], s3a[4];
        if ((tid & 63) == 0) { sd[wid] = ls; s1a[wid] = lc; s2a[wid] = cr; s3a[wid] = vl; }
        __syncthreads();
        if (tid == 0) {
            const double L = sd[0] + sd[1] + sd[2] + sd[3];
            const int c1 = s1a[0] + s1a[1] + s1a[2] + s1a[3];
            const int c2 = s2a[0] + s2a[1] + s2a[2] + s2a[3];
            const int c3 = s3a[0] + s3a[1] + s3a[2] + s3a[3];
            out[0] = (c1 > 0) ? (float)(L / (double)c1) : 0.0f;
            out[1] = (c3 > 0) ? ((float)c2 / (float)c3) : 0.0f;
        }
    }
}

extern "C" void kernel_launch(void* const* d_in, const int* in_sizes, int n_in,
                              void* d_out, int out_size, void* d_ws, size_t ws_size,
                              hipStream_t stream) {
    const float* pred   = (const float*)d_in[0];
    const float* target = (const float*)d_in[1];
    uint2*   wsT  = (uint2*)d_ws;
    Partial* part = (Partial*)((char*)d_ws + TGT_BYTES);
    int* counter  = (int*)((char*)d_ws + TGT_BYTES + (size_t)NBLKB * sizeof(Partial));
    float* out = (float*)d_out;
    hipLaunchKernelGGL(tdoa_targets, dim3(NBLKA), dim3(256), 0, stream, target, wsT, counter);
    hipLaunchKernelGGL(tdoa_loss,    dim3(NBLKB), dim3(256), 0, stream, pred, wsT, part, counter, out);
}

// Round 8
// 161.030 us; speedup vs baseline: 1.3602x; 1.3602x over previous
//
#include <hip/hip_runtime.h>
#include <cstdint>
#include <cstddef>

#define BT_TOTAL 76800   // 128*600 cells
#define NCLS 13
#define IGN  (-100)

// ---- kernel A: targets ----
#define CPA   32                 // cells per block (25 KB LDS -> 6 blocks/CU)
#define NBLKA (BT_TOTAL / CPA)   // 2400
#define NF4A  (CPA * 195 / 4)    // 1560 float4
#define KA    7                  // ceil(1560/256)
// ---- kernel B: loss ----
#define CPB   32                 // cells per block
#define NBLKB (BT_TOTAL / CPB)   // 2400
#define ITEMS (CPB * 6)          // 192
#define NF4B  (CPB * 234 / 4)    // 1872 float4
#define KB    8                  // ceil(1872/256)

// d_ws layout:
//   [0 .. TGT_BYTES)             uint2  packed targets {ta bytes, tb bytes}
//   [TGT_BYTES .. +NBLKB*16)     Partial per block
#define TGT_BYTES ((size_t)BT_TOTAL * 6 * sizeof(uint2))   // 3,686,400

struct Partial { float ls; int lc; int cor; int val; };

// async global->LDS DMA, 16B per lane; dest = wave-uniform base + lane*16
__device__ __forceinline__ void stage16(const float4* __restrict__ g, float4* l) {
    __builtin_amdgcn_global_load_lds((const __attribute__((address_space(1))) void*)g,
                                     (__attribute__((address_space(3))) void*)l,
                                     16, 0, 0);
}

// ================= Kernel A: TDOA targets =================
extern "C" __global__ __launch_bounds__(256)
void tdoa_targets(const float* __restrict__ target, uint2* __restrict__ wsT) {
    const int tid = threadIdx.x;
    const int cb  = blockIdx.x * CPA;

    __shared__ float4 sA4[NF4A];   // 24,960 B
    const float* sA = (const float*)sA4;

    {
        const float4* g = (const float4*)(target + (size_t)cb * 195);
#pragma unroll
        for (int k = 0; k < KA; k++) {
            const int i = k * 256 + tid;
            if (i < NF4A) stage16(g + i, &sA4[i]);
        }
    }
    __syncthreads();   // drains the global_load_lds queue

    if (tid < CPA) {
        const float* tg = sA + tid * 195;   // [e][f][c] : e*65 + f*13 + c

        const float MX[4] = { 0.02432757455f,  0.02432757455f, -0.02432757455f, -0.02432757455f };
        const float MY[4] = { 0.02432757455f, -0.02432757455f,  0.02432757455f, -0.02432757455f };
        const float MZ[4] = { 0.02409021033f, -0.02409021033f, -0.02409021033f,  0.02409021033f };
        const int PI_[6] = {0,0,0,1,1,2};
        const int PJ_[6] = {1,2,3,2,3,3};

        int  td[3][6];
        bool ab[3];
        int  nact = 0;
#pragma unroll
        for (int e = 0; e < 3; e++) {
            float a[NCLS];
#pragma unroll
            for (int c = 0; c < NCLS; c++) a[c] = tg[e * 65 + c];
            bool ia = false;
#pragma unroll
            for (int c = 0; c < NCLS; c++) ia = ia || (a[c] > 0.0f);
            float d0 = 0.f, d1 = 0.f, d2 = 0.f, ds = 0.f;
#pragma unroll
            for (int c = 0; c < NCLS; c++) {
                d0 += a[c] * tg[e * 65 + 13 + c];
                d1 += a[c] * tg[e * 65 + 26 + c];
                d2 += a[c] * tg[e * 65 + 39 + c];
                ds += a[c] * tg[e * 65 + 52 + c];
            }
            const float sx = d0 * ds, sy = d1 * ds, sz = d2 * ds;
            float dm[4];
#pragma unroll
            for (int m = 0; m < 4; m++) {
                const float ex = sx - MX[m], ey = sy - MY[m], ez = sz - MZ[m];
                dm[m] = sqrtf(ex * ex + ey * ey + ez * ez);
            }
#pragma unroll
            for (int p = 0; p < 6; p++) {
                const float diff = dm[PI_[p]] - dm[PJ_[p]];
                td[e][p] = (int)rintf((diff * 24000.0f) / 343.0f) + 6;  // MAX_TAU=6
            }
            ab[e] = ia;
            nact += ia ? 1 : 0;
        }

        // stable argsort(!is_active) for E=3: actives first, original order
        const int o0 = ab[0] ? 0 : (ab[1] ? 1 : 2);
        const int o1 = (ab[0] && ab[1]) ? 1 : 2;
        const bool empty = (nact == 0);

#pragma unroll
        for (int p = 0; p < 6; p++) {
            const int g0 = (o0 == 0) ? td[0][p] : ((o0 == 1) ? td[1][p] : td[2][p]);
            const int g1 = (o1 == 1) ? td[1][p] : td[2][p];
            const int g2 = td[2][p];
            // idx1 = clip(min(k, n-1), 0, 2); idx2 = (k < n) ? k : 0
            int ta0 = g0;
            int ta1 = (nact >= 2) ? g1 : g0;
            int ta2 = (nact == 3) ? g2 : ((nact == 2) ? g1 : g0);
            int tb0 = g0;
            int tb1 = (nact >= 2) ? g1 : g0;
            int tb2 = (nact == 3) ? g2 : g0;
            uint32_t w0 = (uint32_t)(ta0 & 0xff) | ((uint32_t)(ta1 & 0xff) << 8) | ((uint32_t)(ta2 & 0xff) << 16);
            uint32_t w1 = (uint32_t)(tb0 & 0xff) | ((uint32_t)(tb1 & 0xff) << 8) | ((uint32_t)(tb2 & 0xff) << 16);
            if (empty) { w0 = 0x009c9c9cu; w1 = 0x009c9c9cu; }   // 0x9c == (int8)-100
            wsT[(size_t)(cb + tid) * 6 + p] = make_uint2(w0, w1);
        }
    }
}

// ================= Kernel B: PIT loss =================
extern "C" __global__ __launch_bounds__(256)
void tdoa_loss(const float* __restrict__ pred, const uint2* __restrict__ wsT,
               Partial* __restrict__ part) {
    const int tid = threadIdx.x;
    const int cb  = blockIdx.x * CPB;

    __shared__ float4 sP4[NF4B];   // 29,952 B -> 5 blocks/CU
    const float* sP = (const float*)sP4;

    {
        const float4* g = (const float4*)(pred + (size_t)cb * 234);
#pragma unroll
        for (int k = 0; k < KB; k++) {
            const int i = k * 256 + tid;
            if (i < NF4B) stage16(g + i, &sP4[i]);
        }
    }
    __syncthreads();   // drains the global_load_lds queue

    float lsum = 0.f;
    int   lcnt = 0, cor = 0, nval = 0;

    if (tid < ITEMS) {
        const int btl = tid / 6;
        const int p   = tid - btl * 6;
        const float* pp = sP + btl * 234 + p;   // [c][tr][p] strides 18,6,1

        float x[NCLS][3];
#pragma unroll
        for (int c = 0; c < NCLS; c++)
#pragma unroll
            for (int j = 0; j < 3; j++)
                x[c][j] = pp[c * 18 + j * 6];

        int   am[3];
        float lse[3];
#pragma unroll
        for (int j = 0; j < 3; j++) {
            float m = x[0][j]; int a = 0;
#pragma unroll
            for (int c = 1; c < NCLS; c++) { if (x[c][j] > m) { m = x[c][j]; a = c; } }
            float s = 0.f;
#pragma unroll
            for (int c = 0; c < NCLS; c++) s += expf(x[c][j] - m);
            am[j] = a; lse[j] = m + logf(s);
        }

        const uint2 tw = wsT[(size_t)(cb + btl) * 6 + p];   // coalesced dwordx2
        int ta[3], tb[3];
#pragma unroll
        for (int i = 0; i < 3; i++) {
            ta[i] = (int)(int8_t)(tw.x >> (8 * i));
            tb[i] = (int)(int8_t)(tw.y >> (8 * i));
        }

        // indexed LDS reads instead of 13-deep cndmask select chains
        float La[3][3], Lb[3][3];
#pragma unroll
        for (int i = 0; i < 3; i++) {
            const int  ca  = (ta[i] < 0) ? 0 : ta[i];
            const int  cb2 = (tb[i] < 0) ? 0 : tb[i];
            const bool ia  = (ta[i] == IGN);
            const bool ib  = (tb[i] == IGN);
#pragma unroll
            for (int j = 0; j < 3; j++) {
                La[i][j] = ia ? 0.f : (lse[j] - pp[ca  * 18 + j * 6]);
                Lb[i][j] = ib ? 0.f : (lse[j] - pp[cb2 * 18 + j * 6]);
            }
        }

        const int P0[6] = {0,0,1,1,2,2};
        const int P1[6] = {1,2,0,2,0,1};
        const int P2[6] = {2,1,2,0,1,0};
        float l1 = 0.f, l2 = 0.f; int i1 = 0, i2 = 0;
#pragma unroll
        for (int q = 0; q < 6; q++) {
            const float va = (La[0][P0[q]] + La[1][P1[q]] + La[2][P2[q]]) * (1.0f / 3.0f);
            const float vb = (Lb[0][P0[q]] + Lb[1][P1[q]] + Lb[2][P2[q]]) * (1.0f / 3.0f);
            if (q == 0) { l1 = va; l2 = vb; }
            else {
                if (va < l1) { l1 = va; i1 = q; }
                if (vb < l2) { l2 = vb; i2 = q; }
            }
        }

        const bool use2 = (l2 < l1);
        const float loss = use2 ? l2 : l1;
        const int  qsel = use2 ? i2 : i1;
        const int PK[6] = {36, 24, 33, 9, 18, 6};   // p0 | p1<<2 | p2<<4
        int pk = PK[0];
#pragma unroll
        for (int k = 1; k < 6; k++) pk = (qsel == k) ? PK[k] : pk;
        const int s0 = use2 ? tb[0] : ta[0];
        const int s1 = use2 ? tb[1] : ta[1];
        const int s2 = use2 ? tb[2] : ta[2];
#pragma unroll
        for (int i = 0; i < 3; i++) {
            const int pi = (pk >> (2 * i)) & 3;
            const int tp = (pi == 0) ? s0 : ((pi == 1) ? s1 : s2);
            const bool v = (tp != IGN);
            nval += v ? 1 : 0;
            cor  += (v && (am[i] == tp)) ? 1 : 0;
        }
        if (loss > 0.f) { lsum += loss; lcnt++; }
    }

    // block reduction (4 waves) -> per-block partial, NO atomics
#pragma unroll
    for (int off = 32; off > 0; off >>= 1) {
        lsum += __shfl_down(lsum, off, 64);
        lcnt += __shfl_down(lcnt, off, 64);
        cor  += __shfl_down(cor,  off, 64);
        nval += __shfl_down(nval, off, 64);
    }
    __shared__ float rf[4];
    __shared__ int   r1[4], r2[4], r3[4];
    const int wid = tid >> 6;
    if ((tid & 63) == 0) { rf[wid] = lsum; r1[wid] = lcnt; r2[wid] = cor; r3[wid] = nval; }
    __syncthreads();
    if (tid == 0) {
        Partial pt;
        pt.ls  = rf[0] + rf[1] + rf[2] + rf[3];
        pt.lc  = r1[0] + r1[1] + r1[2] + r1[3];
        pt.cor = r2[0] + r2[1] + r2[2] + r2[3];
        pt.val = r3[0] + r3[1] + r3[2] + r3[3];
        part[blockIdx.x] = pt;
    }
}

// ================= Final reduce =================
extern "C" __global__ __launch_bounds__(256)
void tdoa_final(const Partial* __restrict__ part, float* __restrict__ out) {
    const int tid = threadIdx.x;
    double ls = 0.0; int lc = 0, cor = 0, val = 0;
    for (int i = tid; i < NBLKB; i += 256) {
        const Partial p = part[i];
        ls += (double)p.ls; lc += p.lc; cor += p.cor; val += p.val;
    }
#pragma unroll
    for (int off = 32; off > 0; off >>= 1) {
        ls  += __shfl_down(ls,  off, 64);
        lc  += __shfl_down(lc,  off, 64);
        cor += __shfl_down(cor, off, 64);
        val += __shfl_down(val, off, 64);
    }
    __shared__ double sd[4];
    __shared__ int    s1[4], s2[4], s3[4];
    const int wid = tid >> 6;
    if ((tid & 63) == 0) { sd[wid] = ls; s1[wid] = lc; s2[wid] = cor; s3[wid] = val; }
    __syncthreads();
    if (tid == 0) {
        const double L = sd[0] + sd[1] + sd[2] + sd[3];
        const int c1 = s1[0] + s1[1] + s1[2] + s1[3];
        const int c2 = s2[0] + s2[1] + s2[2] + s2[3];
        const int c3 = s3[0] + s3[1] + s3[2] + s3[3];
        out[0] = (c1 > 0) ? (float)(L / (double)c1) : 0.0f;
        out[1] = (c3 > 0) ? ((float)c2 / (float)c3) : 0.0f;
    }
}

extern "C" void kernel_launch(void* const* d_in, const int* in_sizes, int n_in,
                              void* d_out, int out_size, void* d_ws, size_t ws_size,
                              hipStream_t stream) {
    const float* pred   = (const float*)d_in[0];
    const float* target = (const float*)d_in[1];
    uint2*   wsT  = (uint2*)d_ws;
    Partial* part = (Partial*)((char*)d_ws + TGT_BYTES);
    float* out = (float*)d_out;
    hipLaunchKernelGGL(tdoa_targets, dim3(NBLKA), dim3(256), 0, stream, target, wsT);
    hipLaunchKernelGGL(tdoa_loss,    dim3(NBLKB), dim3(256), 0, stream, pred, wsT, part);
    hipLaunchKernelGGL(tdoa_final,   dim3(1),     dim3(256), 0, stream, part, out);
}

// Round 9
// 152.472 us; speedup vs baseline: 1.4365x; 1.0561x over previous
//
#include <hip/hip_runtime.h>
#include <cstdint>
#include <cstddef>

#define BT_TOTAL 76800   // 128*600 cells
#define NCLS 13
#define IGN  (-100)

#define CPB   32                 // cells per block
#define NBLK  (BT_TOTAL / CPB)   // 2400
#define ITEMS (CPB * 6)          // 192
#define NF4T  (CPB * 195 / 4)    // 1560 float4 (target region)
#define KT    7                  // ceil(1560/256)
#define NF4P  (CPB * 234 / 4)    // 1872 float4 (pred region)
#define KP    8                  // ceil(1872/256)

struct Partial { float ls; int lc; int cor; int val; };

// async global->LDS DMA, 16B per lane; dest = wave-uniform base + lane*16
__device__ __forceinline__ void stage16(const float4* __restrict__ g, float4* l) {
    __builtin_amdgcn_global_load_lds((const __attribute__((address_space(1))) void*)g,
                                     (__attribute__((address_space(3))) void*)l,
                                     16, 0, 0);
}

// ====== Fused kernel: sequential LDS reuse (target -> phase1 -> pred -> phase2) ======
extern "C" __global__ __launch_bounds__(256)
void tdoa_fused(const float* __restrict__ pred, const float* __restrict__ target,
                Partial* __restrict__ part) {
    const int tid = threadIdx.x;
    const int cb  = blockIdx.x * CPB;

    __shared__ float4 sBuf4[NF4P];      // 29,952 B, reused for both stages
    __shared__ uint32_t sTd[CPB * 12];  //  1,536 B packed {ta,tb} per (cell,pair)
    const float* sBuf = (const float*)sBuf4;
    // total LDS ~31.5 KB -> 5 blocks/CU

    // ---- stage 1: target, async DMA ----
    {
        const float4* gt = (const float4*)(target + (size_t)cb * 195);
#pragma unroll
        for (int k = 0; k < KT; k++) {
            const int i = k * 256 + tid;
            if (i < NF4T) stage16(gt + i, &sBuf4[i]);
        }
    }
    __syncthreads();   // drain DMA queue

    // ---- phase 1: TDOA targets, one thread per cell ----
    if (tid < CPB) {
        const float* tg = sBuf + tid * 195;   // [e][f][c] : e*65 + f*13 + c

        const float MX[4] = { 0.02432757455f,  0.02432757455f, -0.02432757455f, -0.02432757455f };
        const float MY[4] = { 0.02432757455f, -0.02432757455f,  0.02432757455f, -0.02432757455f };
        const float MZ[4] = { 0.02409021033f, -0.02409021033f, -0.02409021033f,  0.02409021033f };
        const int PI_[6] = {0,0,0,1,1,2};
        const int PJ_[6] = {1,2,3,2,3,3};

        int  td[3][6];
        bool ab[3];
        int  nact = 0;
#pragma unroll
        for (int e = 0; e < 3; e++) {
            float a[NCLS];
#pragma unroll
            for (int c = 0; c < NCLS; c++) a[c] = tg[e * 65 + c];
            bool ia = false;
#pragma unroll
            for (int c = 0; c < NCLS; c++) ia = ia || (a[c] > 0.0f);
            float d0 = 0.f, d1 = 0.f, d2 = 0.f, ds = 0.f;
#pragma unroll
            for (int c = 0; c < NCLS; c++) {
                d0 += a[c] * tg[e * 65 + 13 + c];
                d1 += a[c] * tg[e * 65 + 26 + c];
                d2 += a[c] * tg[e * 65 + 39 + c];
                ds += a[c] * tg[e * 65 + 52 + c];
            }
            const float sx = d0 * ds, sy = d1 * ds, sz = d2 * ds;
            float dm[4];
#pragma unroll
            for (int m = 0; m < 4; m++) {
                const float ex = sx - MX[m], ey = sy - MY[m], ez = sz - MZ[m];
                dm[m] = sqrtf(ex * ex + ey * ey + ez * ez);
            }
#pragma unroll
            for (int p = 0; p < 6; p++) {
                const float diff = dm[PI_[p]] - dm[PJ_[p]];
                td[e][p] = (int)rintf((diff * 24000.0f) / 343.0f) + 6;  // MAX_TAU=6
            }
            ab[e] = ia;
            nact += ia ? 1 : 0;
        }

        // stable argsort(!is_active) for E=3: actives first, original order
        const int o0 = ab[0] ? 0 : (ab[1] ? 1 : 2);
        const int o1 = (ab[0] && ab[1]) ? 1 : 2;
        const bool empty = (nact == 0);

#pragma unroll
        for (int p = 0; p < 6; p++) {
            const int g0 = (o0 == 0) ? td[0][p] : ((o0 == 1) ? td[1][p] : td[2][p]);
            const int g1 = (o1 == 1) ? td[1][p] : td[2][p];
            const int g2 = td[2][p];
            // idx1 = clip(min(k, n-1), 0, 2); idx2 = (k < n) ? k : 0
            int ta0 = g0;
            int ta1 = (nact >= 2) ? g1 : g0;
            int ta2 = (nact == 3) ? g2 : ((nact == 2) ? g1 : g0);
            int tb0 = g0;
            int tb1 = (nact >= 2) ? g1 : g0;
            int tb2 = (nact == 3) ? g2 : g0;
            uint32_t w0 = (uint32_t)(ta0 & 0xff) | ((uint32_t)(ta1 & 0xff) << 8) | ((uint32_t)(ta2 & 0xff) << 16);
            uint32_t w1 = (uint32_t)(tb0 & 0xff) | ((uint32_t)(tb1 & 0xff) << 8) | ((uint32_t)(tb2 & 0xff) << 16);
            if (empty) { w0 = 0x009c9c9cu; w1 = 0x009c9c9cu; }   // 0x9c == (int8)-100
            sTd[tid * 12 + p * 2 + 0] = w0;
            sTd[tid * 12 + p * 2 + 1] = w1;
        }
    }
    __syncthreads();   // phase1 done reading sBuf -> safe to overwrite

    // ---- stage 2: pred into the SAME buffer, async DMA ----
    {
        const float4* gp = (const float4*)(pred + (size_t)cb * 234);
#pragma unroll
        for (int k = 0; k < KP; k++) {
            const int i = k * 256 + tid;
            if (i < NF4P) stage16(gp + i, &sBuf4[i]);
        }
    }
    __syncthreads();   // drain DMA queue

    // ---- phase 2: one thread per (cell,pair) item ----
    float lsum = 0.f;
    int   lcnt = 0, cor = 0, nval = 0;

    if (tid < ITEMS) {
        const int btl = tid / 6;
        const int p   = tid - btl * 6;
        const float* pp = sBuf + btl * 234 + p;   // [c][tr][p] strides 18,6,1

        float x[NCLS][3];
#pragma unroll
        for (int c = 0; c < NCLS; c++)
#pragma unroll
            for (int j = 0; j < 3; j++)
                x[c][j] = pp[c * 18 + j * 6];

        int   am[3];
        float lse[3];
#pragma unroll
        for (int j = 0; j < 3; j++) {
            float m = x[0][j]; int a = 0;
#pragma unroll
            for (int c = 1; c < NCLS; c++) { if (x[c][j] > m) { m = x[c][j]; a = c; } }
            float s = 0.f;
#pragma unroll
            for (int c = 0; c < NCLS; c++) s += expf(x[c][j] - m);
            am[j] = a; lse[j] = m + logf(s);
        }

        const uint32_t w0 = sTd[btl * 12 + p * 2 + 0];
        const uint32_t w1 = sTd[btl * 12 + p * 2 + 1];
        int ta[3], tb[3];
#pragma unroll
        for (int i = 0; i < 3; i++) {
            ta[i] = (int)(int8_t)(w0 >> (8 * i));
            tb[i] = (int)(int8_t)(w1 >> (8 * i));
        }

        // indexed LDS reads instead of 13-deep cndmask select chains
        float La[3][3], Lb[3][3];
#pragma unroll
        for (int i = 0; i < 3; i++) {
            const int  ca  = (ta[i] < 0) ? 0 : ta[i];
            const int  cb2 = (tb[i] < 0) ? 0 : tb[i];
            const bool ia  = (ta[i] == IGN);
            const bool ib  = (tb[i] == IGN);
#pragma unroll
            for (int j = 0; j < 3; j++) {
                La[i][j] = ia ? 0.f : (lse[j] - pp[ca  * 18 + j * 6]);
                Lb[i][j] = ib ? 0.f : (lse[j] - pp[cb2 * 18 + j * 6]);
            }
        }

        const int P0[6] = {0,0,1,1,2,2};
        const int P1[6] = {1,2,0,2,0,1};
        const int P2[6] = {2,1,2,0,1,0};
        float l1 = 0.f, l2 = 0.f; int i1 = 0, i2 = 0;
#pragma unroll
        for (int q = 0; q < 6; q++) {
            const float va = (La[0][P0[q]] + La[1][P1[q]] + La[2][P2[q]]) * (1.0f / 3.0f);
            const float vb = (Lb[0][P0[q]] + Lb[1][P1[q]] + Lb[2][P2[q]]) * (1.0f / 3.0f);
            if (q == 0) { l1 = va; l2 = vb; }
            else {
                if (va < l1) { l1 = va; i1 = q; }
                if (vb < l2) { l2 = vb; i2 = q; }
            }
        }

        const bool use2 = (l2 < l1);
        const float loss = use2 ? l2 : l1;
        const int  qsel = use2 ? i2 : i1;
        const int PK[6] = {36, 24, 33, 9, 18, 6};   // p0 | p1<<2 | p2<<4
        int pk = PK[0];
#pragma unroll
        for (int k = 1; k < 6; k++) pk = (qsel == k) ? PK[k] : pk;
        const int s0 = use2 ? tb[0] : ta[0];
        const int s1 = use2 ? tb[1] : ta[1];
        const int s2 = use2 ? tb[2] : ta[2];
#pragma unroll
        for (int i = 0; i < 3; i++) {
            const int pi = (pk >> (2 * i)) & 3;
            const int tp = (pi == 0) ? s0 : ((pi == 1) ? s1 : s2);
            const bool v = (tp != IGN);
            nval += v ? 1 : 0;
            cor  += (v && (am[i] == tp)) ? 1 : 0;
        }
        if (loss > 0.f) { lsum += loss; lcnt++; }
    }

    // block reduction (4 waves) -> per-block partial, NO atomics
#pragma unroll
    for (int off = 32; off > 0; off >>= 1) {
        lsum += __shfl_down(lsum, off, 64);
        lcnt += __shfl_down(lcnt, off, 64);
        cor  += __shfl_down(cor,  off, 64);
        nval += __shfl_down(nval, off, 64);
    }
    __shared__ float rf[4];
    __shared__ int   r1[4], r2[4], r3[4];
    const int wid = tid >> 6;
    if ((tid & 63) == 0) { rf[wid] = lsum; r1[wid] = lcnt; r2[wid] = cor; r3[wid] = nval; }
    __syncthreads();
    if (tid == 0) {
        Partial pt;
        pt.ls  = rf[0] + rf[1] + rf[2] + rf[3];
        pt.lc  = r1[0] + r1[1] + r1[2] + r1[3];
        pt.cor = r2[0] + r2[1] + r2[2] + r2[3];
        pt.val = r3[0] + r3[1] + r3[2] + r3[3];
        part[blockIdx.x] = pt;
    }
}

// ================= Final reduce =================
extern "C" __global__ __launch_bounds__(256)
void tdoa_final(const Partial* __restrict__ part, float* __restrict__ out) {
    const int tid = threadIdx.x;
    double ls = 0.0; int lc = 0, cor = 0, val = 0;
    for (int i = tid; i < NBLK; i += 256) {
        const Partial p = part[i];
        ls += (double)p.ls; lc += p.lc; cor += p.cor; val += p.val;
    }
#pragma unroll
    for (int off = 32; off > 0; off >>= 1) {
        ls  += __shfl_down(ls,  off, 64);
        lc  += __shfl_down(lc,  off, 64);
        cor += __shfl_down(cor, off, 64);
        val += __shfl_down(val, off, 64);
    }
    __shared__ double sd[4];
    __shared__ int    s1[4], s2[4], s3[4];
    const int wid = tid >> 6;
    if ((tid & 63) == 0) { sd[wid] = ls; s1[wid] = lc; s2[wid] = cor; s3[wid] = val; }
    __syncthreads();
    if (tid == 0) {
        const double L = sd[0] + sd[1] + sd[2] + sd[3];
        const int c1 = s1[0] + s1[1] + s1[2] + s1[3];
        const int c2 = s2[0] + s2[1] + s2[2] + s2[3];
        const int c3 = s3[0] + s3[1] + s3[2] + s3[3];
        out[0] = (c1 > 0) ? (float)(L / (double)c1) : 0.0f;
        out[1] = (c3 > 0) ? ((float)c2 / (float)c3) : 0.0f;
    }
}

extern "C" void kernel_launch(void* const* d_in, const int* in_sizes, int n_in,
                              void* d_out, int out_size, void* d_ws, size_t ws_size,
                              hipStream_t stream) {
    const float* pred   = (const float*)d_in[0];
    const float* target = (const float*)d_in[1];
    Partial* part = (Partial*)d_ws;   // 2400 * 16 B = 38,400 B of scratch
    float* out = (float*)d_out;
    hipLaunchKernelGGL(tdoa_fused, dim3(NBLK), dim3(256), 0, stream, pred, target, part);
    hipLaunchKernelGGL(tdoa_final, dim3(1),    dim3(256), 0, stream, part, out);
}